// Round 1
// baseline (529.772 us; speedup 1.0000x reference)
//
#include <hip/hip_runtime.h>
#include <hip/hip_bf16.h>

// ---------------------------------------------------------------------------
// DualRelationsPropagation on MI355X (gfx950)
// N=256 rows, H=768, R=16, L=3.
// Dominant cost: diversity relation GEMM (65536 x 768 x 768 = 77.3 GFLOP)
// -> bf16 MFMA with on-the-fly |x_i - x_j| A-tiles, upper-triangle grid only.
// ---------------------------------------------------------------------------

typedef __attribute__((ext_vector_type(8))) short s16x8;
typedef __attribute__((ext_vector_type(4))) float f32x4;

__device__ __forceinline__ short f2bf_s(float f){
  union { __hip_bfloat16 h; short s; } u; u.h = __float2bfloat16(f); return u.s;
}
__device__ __forceinline__ float bf_s2f(short s){
  union { __hip_bfloat16 h; short s; } u; u.s = s; return __bfloat162float(u.h);
}
__device__ __forceinline__ f32x4 mfma16(s16x8 a, s16x8 b, f32x4 c){
  return __builtin_amdgcn_mfma_f32_16x16x32_bf16(a, b, c, 0, 0, 0);
}

// Swizzled LDS addressing. Tiles are row-major [rows][64] bf16 (128B rows) or
// [rows][128] bf16 (256B rows). XOR of (row&7)<<4 into the byte offset kills
// the 16-way bank conflict of stride-128B/256B column reads (G4 / T2).
__device__ __forceinline__ char* swz64(short* base, int row, int col){
  int byte = (row << 7) + (col << 1);
  byte ^= (row & 7) << 4;
  return (char*)base + byte;
}
__device__ __forceinline__ char* swz256(short* base, int row, int col){
  int byte = (row << 8) + (col << 1);
  byte ^= (row & 7) << 4;
  return (char*)base + byte;
}

// ---------------------------------------------------------------------------
// Generic bf16 GEMM: C(MxN) = A(MxK) * B^T   (B stored N x K row-major).
// BM,BN tile; BK=64; 256 threads = 4 waves in 2x2; per-wave (BM/2)x(BN/2).
// EPI: 0 = f32 out, 1 = +bias -> bf16, 2 = relu(+bias) -> bf16, 3 = +bias -> f32
// M,N,K multiples of 64. Register-staged LDS with XOR swizzle.
// ---------------------------------------------------------------------------
template<int BM, int BN, int EPI>
__global__ __launch_bounds__(256) void gemm_bt(
    const short* __restrict__ A, int lda,
    const short* __restrict__ B, int ldb,
    float* __restrict__ Cf, short* __restrict__ Cb, int ldc,
    const float* __restrict__ bias, int K, int NT)
{
  __shared__ short As[BM*64];
  __shared__ short Bs[BN*64];
  const int tid = threadIdx.x, lane = tid & 63, wid = tid >> 6;
  const int nt = blockIdx.x % NT, mt = blockIdx.x / NT;
  const int m0 = mt*BM, n0 = nt*BN;
  const int wm0 = (wid>>1)*(BM/2), wn0 = (wid&1)*(BN/2);
  f32x4 acc[BM/32][BN/32] = {};
  for (int k0 = 0; k0 < K; k0 += 64){
    #pragma unroll
    for (int rd = 0; rd < (BM*64)/2048; ++rd){
      int ei = rd*2048 + tid*8, row = ei>>6, col = ei&63;
      *(uint4*)swz64(As,row,col) = *(const uint4*)(A + (size_t)(m0+row)*lda + k0 + col);
    }
    #pragma unroll
    for (int rd = 0; rd < (BN*64)/2048; ++rd){
      int ei = rd*2048 + tid*8, row = ei>>6, col = ei&63;
      *(uint4*)swz64(Bs,row,col) = *(const uint4*)(B + (size_t)(n0+row)*ldb + k0 + col);
    }
    __syncthreads();
    #pragma unroll
    for (int kk = 0; kk < 2; ++kk){
      const int kc = kk*32 + (lane>>4)*8;
      s16x8 af[BM/32], bfv[BN/32];
      #pragma unroll
      for (int mi = 0; mi < BM/32; ++mi)
        af[mi] = *(const s16x8*)swz64(As, wm0 + mi*16 + (lane&15), kc);
      #pragma unroll
      for (int ni = 0; ni < BN/32; ++ni)
        bfv[ni] = *(const s16x8*)swz64(Bs, wn0 + ni*16 + (lane&15), kc);
      #pragma unroll
      for (int mi = 0; mi < BM/32; ++mi)
        #pragma unroll
        for (int ni = 0; ni < BN/32; ++ni)
          acc[mi][ni] = mfma16(af[mi], bfv[ni], acc[mi][ni]);
    }
    __syncthreads();
  }
  // C/D layout (m89-verified): col = lane&15, row = (lane>>4)*4 + reg
  #pragma unroll
  for (int mi = 0; mi < BM/32; ++mi){
    #pragma unroll
    for (int ni = 0; ni < BN/32; ++ni){
      const int gcol = n0 + wn0 + ni*16 + (lane&15);
      float bv = (EPI != 0) ? bias[gcol] : 0.f;
      #pragma unroll
      for (int r = 0; r < 4; ++r){
        const int grow = m0 + wm0 + mi*16 + (lane>>4)*4 + r;
        float v = acc[mi][ni][r] + bv;
        if (EPI == 2) v = fmaxf(v, 0.f);
        if (EPI == 0 || EPI == 3) Cf[(size_t)grow*ldc + gcol] = v;
        else                      Cb[(size_t)grow*ldc + gcol] = f2bf_s(v);
      }
    }
  }
}

// ---------------------------------------------------------------------------
// msg GEMM: C(MxN) = A(MxK) * B(KxN), B in natural K-major layout (= T buffer
// reinterpreted as (4096 x 768)). B staged TRANSPOSED into LDS via swizzled
// ds_write_b16 (conflict-free: bank = 4e + k/2, all distinct). 64x64 tile.
// Epilogue: *scale -> bf16 into comb[:, ccol0+..].
// ---------------------------------------------------------------------------
__global__ __launch_bounds__(256) void gemm_bn_msg(
    const short* __restrict__ A, int lda,
    const short* __restrict__ B, int ldb,
    short* __restrict__ Co, int ldc, int ccol0,
    int K, int NT, float scale)
{
  __shared__ short As[64*64];
  __shared__ short Bs[64*64];
  const int tid = threadIdx.x, lane = tid & 63, wid = tid >> 6;
  const int nt = blockIdx.x % NT, mt = blockIdx.x / NT;
  const int m0 = mt*64, n0 = nt*64;
  const int wm0 = (wid>>1)*32, wn0 = (wid&1)*32;
  f32x4 acc[2][2] = {};
  for (int k0 = 0; k0 < K; k0 += 64){
    #pragma unroll
    for (int rd = 0; rd < 2; ++rd){
      int ei = rd*2048 + tid*8, row = ei>>6, col = ei&63;
      *(uint4*)swz64(As,row,col) = *(const uint4*)(A + (size_t)(m0+row)*lda + k0 + col);
    }
    #pragma unroll
    for (int rd = 0; rd < 2; ++rd){
      int ei = rd*2048 + tid*8, kr = ei>>6, nc = ei&63;
      union { uint4 v; short s[8]; } u;
      u.v = *(const uint4*)(B + (size_t)(k0+kr)*ldb + n0 + nc);
      #pragma unroll
      for (int e = 0; e < 8; ++e)
        *(short*)swz64(Bs, nc+e, kr) = u.s[e];   // Bs[n][k] = B[k,n]
    }
    __syncthreads();
    #pragma unroll
    for (int kk = 0; kk < 2; ++kk){
      const int kc = kk*32 + (lane>>4)*8;
      s16x8 af[2], bfv[2];
      #pragma unroll
      for (int mi = 0; mi < 2; ++mi)
        af[mi] = *(const s16x8*)swz64(As, wm0 + mi*16 + (lane&15), kc);
      #pragma unroll
      for (int ni = 0; ni < 2; ++ni)
        bfv[ni] = *(const s16x8*)swz64(Bs, wn0 + ni*16 + (lane&15), kc);
      #pragma unroll
      for (int mi = 0; mi < 2; ++mi)
        #pragma unroll
        for (int ni = 0; ni < 2; ++ni)
          acc[mi][ni] = mfma16(af[mi], bfv[ni], acc[mi][ni]);
    }
    __syncthreads();
  }
  #pragma unroll
  for (int mi = 0; mi < 2; ++mi)
    #pragma unroll
    for (int ni = 0; ni < 2; ++ni){
      const int gcol = n0 + wn0 + ni*16 + (lane&15);
      #pragma unroll
      for (int r = 0; r < 4; ++r){
        const int grow = m0 + wm0 + mi*16 + (lane>>4)*4 + r;
        Co[(size_t)grow*ldc + ccol0 + gcol] = f2bf_s(acc[mi][ni][r] * scale);
      }
    }
}

// ---------------------------------------------------------------------------
// Pair-logits kernel (the monster + its sim twin).
// Grid: x in [0,384): bx<256 -> (i=bx, j-tile=[128,256)); else (i=bx-256<128,
// j-tile=[0,128)) -- covers exactly the upper-triangle source pairs.
// y = n-tile in [0,6) over the 768 channels.
// DIV=true : G = |x_i - x_j| @ wb_div^T via 128x128x768 MFMA K-loop.
// DIV=false: G = pb_sim[j, n] loaded directly.
// Shared epilogue: hid = relu(pa[i,n] + G + b1[n]) -> LDS bf16 ->
//   MFMA (128x16x128) vs w2 chunk -> atomicAdd into logits[i,j,r].
// ---------------------------------------------------------------------------
template<bool DIV>
__global__ __launch_bounds__(256) void pair_logits(
    const short* __restrict__ xb,      // comb base, rows stride 1536, x in cols [0,768)
    const short* __restrict__ wbdiv,   // 768x768 bf16 (B^T layout), DIV only
    const float* __restrict__ P,       // 256x2304: [pa_sim | pb_sim | pa_div]
    const float* __restrict__ b1,
    const short* __restrict__ w2b,     // 16x768 bf16
    float* __restrict__ logits)        // 256*256*16 f32 (atomic accum)
{
  const int bx = blockIdx.x, nt = blockIdx.y;
  int i, j0;
  if (bx < 256){ i = bx; j0 = 128; } else { i = bx - 256; j0 = 0; }
  const int n0 = nt*128;
  const int tid = threadIdx.x, lane = tid & 63, wid = tid >> 6;

  __shared__ short smem[16384];        // 32KB: As(16K)+Bs(16K), reused as hids
  __shared__ short w2s[16*128];        // 4KB
  __shared__ float pab[128];
  short* As = smem; short* Bs = smem + 8192; short* hids = smem;

  if (tid < 128){
    const float* pa = P + (size_t)i*2304 + (DIV ? 1536 : 0);
    pab[tid] = pa[n0+tid] + b1[n0+tid];
  }
  { // stage w2 chunk (16 x 128) into [16][128] swizzled
    int ei = tid*8, r = ei>>7, c = ei&127;
    *(uint4*)swz256(w2s, r, c) = *(const uint4*)(w2b + (size_t)r*768 + n0 + c);
  }

  if (DIV){
    f32x4 acc[4][4] = {};
    for (int k0 = 0; k0 < 768; k0 += 64){
      #pragma unroll
      for (int rd = 0; rd < 4; ++rd){   // A = |x_i - x_j| tile, built on the fly
        int ei = rd*2048 + tid*8, row = ei>>6, col = ei&63;
        union { uint4 v; short s[8]; } uj, ui, uo;
        uj.v = *(const uint4*)(xb + (size_t)(j0+row)*1536 + k0 + col);
        ui.v = *(const uint4*)(xb + (size_t)i*1536 + k0 + col);
        #pragma unroll
        for (int e = 0; e < 8; ++e)
          uo.s[e] = f2bf_s(fabsf(bf_s2f(uj.s[e]) - bf_s2f(ui.s[e])));
        *(uint4*)swz64(As,row,col) = uo.v;
      }
      #pragma unroll
      for (int rd = 0; rd < 4; ++rd){
        int ei = rd*2048 + tid*8, row = ei>>6, col = ei&63;
        *(uint4*)swz64(Bs,row,col) = *(const uint4*)(wbdiv + (size_t)(n0+row)*768 + k0 + col);
      }
      __syncthreads();
      #pragma unroll
      for (int kk = 0; kk < 2; ++kk){
        const int kc = kk*32 + (lane>>4)*8;
        s16x8 af[4], bfv[4];
        #pragma unroll
        for (int mi = 0; mi < 4; ++mi)
          af[mi] = *(const s16x8*)swz64(As, (wid>>1)*64 + mi*16 + (lane&15), kc);
        #pragma unroll
        for (int ni = 0; ni < 4; ++ni)
          bfv[ni] = *(const s16x8*)swz64(Bs, (wid&1)*64 + ni*16 + (lane&15), kc);
        #pragma unroll
        for (int mi = 0; mi < 4; ++mi)
          #pragma unroll
          for (int ni = 0; ni < 4; ++ni)
            acc[mi][ni] = mfma16(af[mi], bfv[ni], acc[mi][ni]);
      }
      __syncthreads();
    }
    // hid = relu(G + pa + b1) -> LDS bf16 [128][128] swizzled
    #pragma unroll
    for (int mi = 0; mi < 4; ++mi)
      #pragma unroll
      for (int ni = 0; ni < 4; ++ni){
        const int col = (wid&1)*64 + ni*16 + (lane&15);
        const float pb_ = pab[col];
        #pragma unroll
        for (int r = 0; r < 4; ++r){
          const int row = (wid>>1)*64 + mi*16 + (lane>>4)*4 + r;
          *(short*)swz256(hids, row, col) = f2bf_s(fmaxf(acc[mi][ni][r] + pb_, 0.f));
        }
      }
  } else {
    __syncthreads();  // pab ready
    #pragma unroll
    for (int rd = 0; rd < 8; ++rd){
      int ei = rd*2048 + tid*8, row = ei>>7, col = ei&127;
      const float* pbp = P + (size_t)(j0+row)*2304 + 768 + n0 + col;
      float4 v0 = *(const float4*)pbp; float4 v1 = *(const float4*)(pbp+4);
      float vv[8] = {v0.x,v0.y,v0.z,v0.w,v1.x,v1.y,v1.z,v1.w};
      union { uint4 v; short s[8]; } uo;
      #pragma unroll
      for (int e = 0; e < 8; ++e)
        uo.s[e] = f2bf_s(fmaxf(vv[e] + pab[col+e], 0.f));
      *(uint4*)swz256(hids, row, col) = uo.v;
    }
  }
  __syncthreads();

  // second GEMM: plog(128 x 16) = hid(128x128) * w2chunk^T(16x128)
  f32x4 acc2[2] = {};
  #pragma unroll
  for (int kk = 0; kk < 4; ++kk){
    const int kc = kk*32 + (lane>>4)*8;
    s16x8 bfr = *(const s16x8*)swz256(w2s, (lane&15), kc);
    #pragma unroll
    for (int f = 0; f < 2; ++f){
      s16x8 afr = *(const s16x8*)swz256(hids, (wid*2+f)*16 + (lane&15), kc);
      acc2[f] = mfma16(afr, bfr, acc2[f]);
    }
  }
  const int r_ = lane & 15;
  #pragma unroll
  for (int f = 0; f < 2; ++f)
    #pragma unroll
    for (int rr = 0; rr < 4; ++rr){
      const int jrow = j0 + (wid*2+f)*16 + (lane>>4)*4 + rr;
      atomicAdd(&logits[(((size_t)i<<8) + jrow)*16 + r_], acc2[f][rr]);
    }
}

// ---------------------------------------------------------------------------
// softmax + symmetrize + C. One thread per (i,j) pair.
// out[i,j] = (i==j) ? 0 : softmax(logits[min,max] + b2); C = 0.5*(sim+div) bf16
// ---------------------------------------------------------------------------
__global__ __launch_bounds__(256) void finisher(
    const float* __restrict__ Ls, const float* __restrict__ Ld,
    const float* __restrict__ b2s, const float* __restrict__ b2d,
    float* __restrict__ simo, float* __restrict__ divo, short* __restrict__ Cb)
{
  const int p = blockIdx.x*256 + threadIdx.x;
  const int i = p >> 8, j = p & 255;
  float so[16], dd[16];
  if (i == j){
    #pragma unroll
    for (int r = 0; r < 16; ++r){ so[r] = 0.f; dd[r] = 0.f; }
  } else {
    const int si = i < j ? i : j, sj = i < j ? j : i;
    const size_t base = (((size_t)si << 8) + sj) * 16;
    float mx = -1e30f, sum;
    #pragma unroll
    for (int r = 0; r < 16; ++r){ so[r] = Ls[base+r] + b2s[r]; mx = fmaxf(mx, so[r]); }
    sum = 0.f;
    #pragma unroll
    for (int r = 0; r < 16; ++r){ so[r] = expf(so[r]-mx); sum += so[r]; }
    sum = 1.f/sum;
    #pragma unroll
    for (int r = 0; r < 16; ++r) so[r] *= sum;
    mx = -1e30f;
    #pragma unroll
    for (int r = 0; r < 16; ++r){ dd[r] = Ld[base+r] + b2d[r]; mx = fmaxf(mx, dd[r]); }
    sum = 0.f;
    #pragma unroll
    for (int r = 0; r < 16; ++r){ dd[r] = expf(dd[r]-mx); sum += dd[r]; }
    sum = 1.f/sum;
    #pragma unroll
    for (int r = 0; r < 16; ++r) dd[r] *= sum;
  }
  const size_t ob = (size_t)p * 16;
  #pragma unroll
  for (int r = 0; r < 16; ++r){
    simo[ob+r] = so[r];
    divo[ob+r] = dd[r];
    Cb[ob+r]   = f2bf_s(0.5f*(so[r]+dd[r]));  // (i, j*16+r) layout == p*16+r
  }
}

// ---------------------------------------------------------------------------
// LayerNorm(y + x) -> x (f32, in place), comb[:, :768] (bf16), optional d_out x
// ---------------------------------------------------------------------------
__global__ __launch_bounds__(256) void ln_kernel(
    const float* __restrict__ y, float* __restrict__ x, short* __restrict__ combx,
    const float* __restrict__ g, const float* __restrict__ b, float* __restrict__ xfinal)
{
  const int row = blockIdx.x, tid = threadIdx.x;
  float tv[3]; float s = 0.f, s2 = 0.f;
  #pragma unroll
  for (int c = 0; c < 3; ++c){
    const int idx = tid + c*256;
    const float v = y[row*768+idx] + x[row*768+idx];
    tv[c] = v; s += v; s2 += v*v;
  }
  #pragma unroll
  for (int off = 32; off > 0; off >>= 1){ s += __shfl_down(s, off); s2 += __shfl_down(s2, off); }
  __shared__ float red[8];
  const int wid = tid >> 6, lane = tid & 63;
  if (lane == 0){ red[wid] = s; red[wid+4] = s2; }
  __syncthreads();
  if (tid == 0){
    red[0] = red[0]+red[1]+red[2]+red[3];
    red[4] = red[4]+red[5]+red[6]+red[7];
  }
  __syncthreads();
  const float mu = red[0]*(1.f/768.f);
  const float var = red[4]*(1.f/768.f) - mu*mu;
  const float inv = rsqrtf(var + 1e-5f);
  #pragma unroll
  for (int c = 0; c < 3; ++c){
    const int idx = tid + c*256;
    const float v = (tv[c]-mu)*inv*g[idx] + b[idx];
    x[row*768+idx] = v;
    combx[(size_t)row*1536 + idx] = f2bf_s(v);
    if (xfinal) xfinal[row*768+idx] = v;
  }
}

// ---------------------------------------------------------------------------
// small conversion / setup kernels
// ---------------------------------------------------------------------------
__global__ void cvt_flat(const float* __restrict__ s, short* __restrict__ d, int n){
  const int i = (blockIdx.x*256 + threadIdx.x)*4;
  if (i >= n) return;
  float4 v = *(const float4*)(s+i);
  union { uint2 u; short s4[4]; } o;
  o.s4[0]=f2bf_s(v.x); o.s4[1]=f2bf_s(v.y); o.s4[2]=f2bf_s(v.z); o.s4[3]=f2bf_s(v.w);
  *(uint2*)(d+i) = o.u;
}

// extract {wa_sim, wb_sim, wa_div, wb_div} (each 768x768) from the two (768,1536) w1s
__global__ void cvt_w1(const float* __restrict__ sw1, const float* __restrict__ dw1,
                       short* __restrict__ dst){
  const int i = (blockIdx.x*256 + threadIdx.x)*4;
  if (i >= 2359296) return;
  const int mat = i / 589824, rem = i % 589824;
  const int r = rem / 768, c = rem % 768;
  const float* src = (mat < 2 ? sw1 : dw1) + (size_t)r*1536 + (mat&1)*768 + c;
  float4 v = *(const float4*)src;
  union { uint2 u; short s4[4]; } o;
  o.s4[0]=f2bf_s(v.x); o.s4[1]=f2bf_s(v.y); o.s4[2]=f2bf_s(v.z); o.s4[3]=f2bf_s(v.w);
  *(uint2*)(dst+i) = o.u;
}

__global__ void concat_x(const float* __restrict__ sup, const float* __restrict__ qry,
                         float* __restrict__ xf, short* __restrict__ comb){
  const int i = (blockIdx.x*256 + threadIdx.x)*4;
  if (i >= 196608) return;
  const int row = i / 768, col = i % 768;
  const float* s = (row < 128 ? sup + (size_t)row*768 : qry + (size_t)(row-128)*768) + col;
  float4 v = *(const float4*)s;
  *(float4*)(xf+i) = v;
  union { uint2 u; short s4[4]; } o;
  o.s4[0]=f2bf_s(v.x); o.s4[1]=f2bf_s(v.y); o.s4[2]=f2bf_s(v.z); o.s4[3]=f2bf_s(v.w);
  *(uint2*)(comb + (size_t)row*1536 + col) = o.u;
}

__global__ void cls2_kernel(const short* __restrict__ hc, const float* __restrict__ w2,
                            const float* __restrict__ b2, float* __restrict__ preds){
  const int t = blockIdx.x*192 + threadIdx.x;
  if (t >= 384) return;
  const int m = t/3, c = t - m*3;
  float s = b2[c];
  for (int k = 0; k < 384; ++k)
    s += bf_s2f(hc[m*384+k]) * w2[c*384+k];
  preds[m*3+c] = s;
}

// ---------------------------------------------------------------------------
// workspace layout (bytes, 256-aligned; total ~54.2 MB)
// ---------------------------------------------------------------------------
static const size_t OFF_LOGITS = 0;          // 8388608  (Ls 4MB | Ld 4MB)
static const size_t OFF_P      = 8388608;    // 2359296  (256x2304 f32)
static const size_t OFF_XF     = 10747904;   // 786432   (256x768 f32)
static const size_t OFF_Y      = 11534336;   // 786432
static const size_t OFF_COMB   = 12320768;   // 786432   (256x1536 bf16)
static const size_t OFF_CB     = 13107200;   // 2097152  (256x4096 bf16)
static const size_t OFF_W1X4   = 15204352;   // 4718592  (4x 768x768 bf16)
static const size_t OFF_W2S    = 19922944;   // 24576
static const size_t OFF_W2D    = 19947520;   // 24576
static const size_t OFF_AW1    = 19972096;   // 7077888  (3x 768x1536 bf16)
static const size_t OFF_AW2    = 27049984;   // 3538944  (3x 768x768 bf16)
static const size_t OFF_CW1    = 30588928;   // 589824   (384x768 bf16)
static const size_t OFF_RWB    = 31178752;   // 18874368 (12288x768 bf16, per-layer)
static const size_t OFF_TBUF   = 50053120;   // 6291456  (256x12288 bf16)
static const size_t OFF_HID1   = 56344576;   // 393216   (256x768 bf16)
static const size_t OFF_HIDC   = 56737792;   // 98304    (128x384 bf16)

extern "C" void kernel_launch(void* const* d_in, const int* in_sizes, int n_in,
                              void* d_out, int out_size, void* d_ws, size_t ws_size,
                              hipStream_t stream)
{
  (void)in_sizes; (void)n_in; (void)out_size; (void)ws_size;
  const float* sup    = (const float*)d_in[0];
  const float* qry    = (const float*)d_in[2];
  const float* sim_w1 = (const float*)d_in[3];
  const float* sim_b1 = (const float*)d_in[4];
  const float* sim_w2 = (const float*)d_in[5];
  const float* sim_b2 = (const float*)d_in[6];
  const float* div_w1 = (const float*)d_in[7];
  const float* div_b1 = (const float*)d_in[8];
  const float* div_w2 = (const float*)d_in[9];
  const float* div_b2 = (const float*)d_in[10];
  const float* rel_w  = (const float*)d_in[11];
  const float* rel_b  = (const float*)d_in[12];
  const float* agg_w1 = (const float*)d_in[13];
  const float* agg_b1 = (const float*)d_in[14];
  const float* agg_w2 = (const float*)d_in[15];
  const float* agg_b2 = (const float*)d_in[16];
  const float* ln_g   = (const float*)d_in[17];
  const float* ln_b   = (const float*)d_in[18];
  const float* cls_w1 = (const float*)d_in[19];
  const float* cls_b1 = (const float*)d_in[20];
  const float* cls_w2 = (const float*)d_in[21];
  const float* cls_b2 = (const float*)d_in[22];

  char* w = (char*)d_ws;
  float* Ls   = (float*)(w + OFF_LOGITS);
  float* Ld   = Ls + 1048576;
  float* P    = (float*)(w + OFF_P);
  float* XF   = (float*)(w + OFF_XF);
  float* Y    = (float*)(w + OFF_Y);
  short* COMB = (short*)(w + OFF_COMB);
  short* CB   = (short*)(w + OFF_CB);
  short* W1X4 = (short*)(w + OFF_W1X4);
  short* W2S  = (short*)(w + OFF_W2S);
  short* W2D  = (short*)(w + OFF_W2D);
  short* AW1  = (short*)(w + OFF_AW1);
  short* AW2  = (short*)(w + OFF_AW2);
  short* CW1  = (short*)(w + OFF_CW1);
  short* RWB  = (short*)(w + OFF_RWB);
  short* TBUF = (short*)(w + OFF_TBUF);
  short* HID1 = (short*)(w + OFF_HID1);
  short* HIDC = (short*)(w + OFF_HIDC);

  float* preds = (float*)d_out;
  float* simo  = preds + 384;
  float* divo  = simo + 1048576;
  float* xout  = divo + 1048576;

  hipMemsetAsync(Ls, 0, 8388608, stream);

  // weight conversions (f32 -> bf16)
  cvt_flat<<<12,   256, 0, stream>>>(sim_w2, W2S, 12288);
  cvt_flat<<<12,   256, 0, stream>>>(div_w2, W2D, 12288);
  cvt_flat<<<3456, 256, 0, stream>>>(agg_w1, AW1, 3538944);
  cvt_flat<<<1728, 256, 0, stream>>>(agg_w2, AW2, 1769472);
  cvt_flat<<<288,  256, 0, stream>>>(cls_w1, CW1, 294912);
  cvt_w1<<<2304,   256, 0, stream>>>(sim_w1, div_w1, W1X4);
  concat_x<<<192,  256, 0, stream>>>(sup, qry, XF, COMB);

  // P = x @ [wa_sim | wb_sim | wa_div]^T   (M=256, N=2304, K=768)
  gemm_bt<64,64,0><<<144, 256, 0, stream>>>(COMB, 1536, W1X4, 768, P, nullptr, 2304,
                                            nullptr, 768, 36);

  // relation logits (upper triangle), atomically accumulated over 6 n-tiles
  pair_logits<true ><<<dim3(384,6), 256, 0, stream>>>(COMB, W1X4 + (size_t)3*589824, P,
                                                      div_b1, W2D, Ld);
  pair_logits<false><<<dim3(384,6), 256, 0, stream>>>(COMB, nullptr, P,
                                                      sim_b1, W2S, Ls);
  finisher<<<256, 256, 0, stream>>>(Ls, Ld, sim_b2, div_b2, simo, divo, CB);

  for (int l = 0; l < 3; ++l){
    cvt_flat<<<9216, 256, 0, stream>>>(rel_w + (size_t)l*9437184, RWB, 9437184);
    // T[j, r*768+k] = sum_h x[j,h] rel_w[r,k,h] + rb   (M=256, N=12288, K=768)
    gemm_bt<64,64,1><<<768, 256, 0, stream>>>(COMB, 1536, RWB, 768, nullptr, TBUF, 12288,
                                              rel_b + l*12288, 768, 192);
    // msg = C(256x4096) * T(4096x768) / 255 -> comb[:, 768:]
    gemm_bn_msg<<<48, 256, 0, stream>>>(CB, 4096, TBUF, 768, COMB, 1536, 768,
                                        4096, 12, 1.f/255.f);
    // hid1 = relu(comb @ aw1^T + ab1)   (M=256, N=768, K=1536)
    gemm_bt<64,64,2><<<48, 256, 0, stream>>>(COMB, 1536, AW1 + (size_t)l*1179648, 1536,
                                             nullptr, HID1, 768, agg_b1 + l*768, 1536, 12);
    // y = hid1 @ aw2^T + ab2            (M=256, N=768, K=768)
    gemm_bt<64,64,3><<<48, 256, 0, stream>>>(HID1, 768, AW2 + (size_t)l*589824, 768,
                                             Y, nullptr, 768, agg_b2 + l*768, 768, 12);
    ln_kernel<<<256, 256, 0, stream>>>(Y, XF, COMB, ln_g + l*768, ln_b + l*768,
                                       (l == 2) ? xout : nullptr);
  }

  // classifier: hidc = relu(q @ cls_w1^T + b1)   (M=128, N=384, K=768)
  gemm_bt<64,64,2><<<12, 256, 0, stream>>>(COMB + (size_t)128*1536, 1536, CW1, 768,
                                           nullptr, HIDC, 384, cls_b1, 768, 6);
  cls2_kernel<<<2, 192, 0, stream>>>(HIDC, cls_w2, cls_b2, preds);
}